// Round 1
// baseline (8363.048 us; speedup 1.0000x reference)
//
#include <hip/hip_runtime.h>

#define T_MAX 8192
#define BATCH 2
#define HID 512
#define KTAGS 60
#define NEGV -10000.0f

// ---------------- conv1: sentence (T,B,3) -> y (B,512,T), relu ----------------
__global__ __launch_bounds__(256) void conv1_kernel(
    const float* __restrict__ sent, const float* __restrict__ w1,
    const float* __restrict__ b1, float* __restrict__ y, int T, int B)
{
    int t = blockIdx.x * 256 + threadIdx.x;
    int c = blockIdx.y;
    int b = blockIdx.z;
    if (t >= T) return;
    float acc = b1[c];
#pragma unroll
    for (int dk = 0; dk < 3; ++dk) {
        int tt = t + dk - 1;
        if (tt >= 0 && tt < T) {
#pragma unroll
            for (int ci = 0; ci < 3; ++ci)
                acc += sent[(size_t)tt * (B * 3) + b * 3 + ci] * w1[c * 9 + ci * 3 + dk];
        }
    }
    y[((size_t)b * HID + c) * T + t] = fmaxf(acc, 0.f);
}

// ---------------- generic conv: y = relu(conv(x1 (+x2), w) + bias) ----------------
// x layout (B,512,T). Tile: 64 cout x 64 t per block, 256 threads, 4x4 per thread.
template<int KTAP, bool RES>
__global__ __launch_bounds__(256) void conv_kernel(
    const float* __restrict__ x1, const float* __restrict__ x2,
    const float* __restrict__ w, const float* __restrict__ bias,
    float* __restrict__ y, int T)
{
    const int PAD = KTAP / 2;
    const int t0 = blockIdx.x * 64;
    const int co0 = blockIdx.y * 64;
    const int b = blockIdx.z;
    __shared__ float Xs[16][72];            // window [t0-2, t0+66)
    __shared__ float Ws[16][KTAP][64];
    const int tid = threadIdx.x;
    const int tx = tid & 15;                // t quad
    const int ty = tid >> 4;                // cout quad
    float acc[4][4] = {};
    const size_t plane = (size_t)HID * T;
    const float* xa = x1 + (size_t)b * plane;
    const float* xb = RES ? (x2 + (size_t)b * plane) : nullptr;

    for (int c0 = 0; c0 < HID; c0 += 16) {
        for (int i = tid; i < 16 * 68; i += 256) {
            int ci = i / 68, tt = i % 68;
            int t = t0 + tt - 2;
            float v = 0.f;
            if (t >= 0 && t < T) {
                size_t off = (size_t)(c0 + ci) * T + t;
                v = xa[off];
                if (RES) v += xb[off];
            }
            Xs[ci][tt] = v;
        }
        for (int i = tid; i < 16 * KTAP * 64; i += 256) {
            int co = i & 63;
            int rest = i >> 6;
            int dk = rest % KTAP;
            int ci = rest / KTAP;
            Ws[ci][dk][co] = w[((size_t)(co0 + co) * HID + (c0 + ci)) * KTAP + dk];
        }
        __syncthreads();
#pragma unroll
        for (int ci = 0; ci < 16; ++ci) {
            float xw[4 + KTAP - 1];
#pragma unroll
            for (int j = 0; j < 4 + KTAP - 1; ++j)
                xw[j] = Xs[ci][tx * 4 + j + (2 - PAD)];
#pragma unroll
            for (int dk = 0; dk < KTAP; ++dk) {
                float wv[4];
#pragma unroll
                for (int r = 0; r < 4; ++r) wv[r] = Ws[ci][dk][ty * 4 + r];
#pragma unroll
                for (int r = 0; r < 4; ++r)
#pragma unroll
                    for (int c = 0; c < 4; ++c)
                        acc[r][c] = fmaf(wv[r], xw[c + dk], acc[r][c]);
            }
        }
        __syncthreads();
    }
#pragma unroll
    for (int r = 0; r < 4; ++r) {
        int co = co0 + ty * 4 + r;
        float bv = bias[co];
#pragma unroll
        for (int c = 0; c < 4; ++c) {
            int t = t0 + tx * 4 + c;
            float v = acc[r][c] + bv;
            y[(size_t)b * plane + (size_t)co * T + t] = fmaxf(v, 0.f);
        }
    }
}

// ---------------- FC: feats[t,b,k] = dot(c5[b,:,t], fc_w[k,:]) + fc_b[k] ----------------
// feats stored padded: feats[(t*2+b)*64 + k]
__global__ __launch_bounds__(256) void fc_kernel(
    const float* __restrict__ x, const float* __restrict__ fw,
    const float* __restrict__ fb, float* __restrict__ feats, int T)
{
    int t0 = blockIdx.x * 64, b = blockIdx.y;
    __shared__ float Xs[64][65];
    __shared__ float Ws[64][60];
    int tid = threadIdx.x;
    int k = tid & 63, tq = tid >> 6;        // k tag, tq: 16-t group
    float acc[16] = {};
    const float* xb = x + (size_t)b * HID * T;
    for (int c0 = 0; c0 < HID; c0 += 64) {
        for (int i = tid; i < 64 * 64; i += 256) {
            int ci = i >> 6, tt = i & 63;
            Xs[ci][tt] = xb[(size_t)(c0 + ci) * T + t0 + tt];
        }
        for (int i = tid; i < 64 * 60; i += 256) {
            int kk = i % 60, ci = i / 60;
            Ws[ci][kk] = fw[(size_t)kk * HID + c0 + ci];
        }
        __syncthreads();
        if (k < KTAGS) {
#pragma unroll 8
            for (int ci = 0; ci < 64; ++ci) {
                float wv = Ws[ci][k];
#pragma unroll
                for (int i = 0; i < 16; ++i)
                    acc[i] = fmaf(wv, Xs[ci][tq * 16 + i], acc[i]);
            }
        }
        __syncthreads();
    }
    if (k < KTAGS) {
        float bv = fb[k];
#pragma unroll
        for (int i = 0; i < 16; ++i) {
            int t = t0 + tq * 16 + i;
            feats[((size_t)t * 2 + b) * 64 + k] = acc[i] + bv;
        }
    }
}

// ---------------- Viterbi forward (sequential, exact op order) ----------------
// block per b; 256 threads = 64 next-tags x 4 prev-sublanes; fv double-buffered in LDS.
__global__ __launch_bounds__(256) void viterbi_fwd(
    const float* __restrict__ feats, const float* __restrict__ trans,
    float* __restrict__ out, unsigned char* __restrict__ bp,
    int* __restrict__ lastinfo, int T)
{
    int b = blockIdx.x;
    int tid = threadIdx.x;
    int next = tid >> 2;
    int sub = tid & 3;
    bool act = next < KTAGS;
    __shared__ float fv[2][64];
    __shared__ float red[64];
    float tr[15];
#pragma unroll
    for (int i = 0; i < 15; ++i)
        tr[i] = act ? trans[next * KTAGS + sub * 15 + i] : -3.0e38f;
    if (tid < 64) fv[0][tid] = (tid == 58) ? 0.f : NEGV;   // START_TAG = 58
    __syncthreads();
    for (int t = 0; t < T; ++t) {
        int cur = t & 1;
        float feat = 0.f;
        if (act && sub == 0) feat = feats[((size_t)t * 2 + b) * 64 + next];
        float m = -3.0e38f;
        int am = sub * 15;
#pragma unroll
        for (int i = 0; i < 15; ++i) {
            float s = fv[cur][sub * 15 + i] + tr[i];
            if (s > m) { m = s; am = sub * 15 + i; }
        }
        // reduce over the 4 sublanes; first-index tie-break => smaller am wins on equal m
#pragma unroll
        for (int d = 1; d < 4; d <<= 1) {
            float om = __shfl_xor(m, d, 64);
            int oam = __shfl_xor(am, d, 64);
            if (om > m || (om == m && oam < am)) { m = om; am = oam; }
        }
        if (act && sub == 0) {
            fv[cur ^ 1][next] = m + feat;
            bp[((size_t)t * 2 + b) * 64 + next] = (unsigned char)am;
        }
        __syncthreads();
    }
    int cur = T & 1;
    if (sub == 0) red[next] = act ? fv[cur][next] + trans[59 * KTAGS + next] : -3.0e38f; // STOP row
    __syncthreads();
    if (tid == 0) {
        float m = red[0];
        int am = 0;
        for (int p = 1; p < KTAGS; ++p)
            if (red[p] > m) { m = red[p]; am = p; }
        out[b] = m;
        lastinfo[b] = am;
    }
}

// ---------------- backtrace, chunked (exact lookups) ----------------
// chunk c covers t in [c*128, c*128+128)
__global__ __launch_bounds__(64) void vit_chunkmap(
    const unsigned char* __restrict__ bp, unsigned char* __restrict__ cmap)
{
    int c = blockIdx.x, b = blockIdx.y;
    __shared__ unsigned char bl[128][64];
    int tid = threadIdx.x;
    const unsigned int* src = (const unsigned int*)bp;
    for (int i = tid; i < 128 * 16; i += 64) {
        int row = i >> 4, q = i & 15;
        ((unsigned int*)&bl[row][0])[q] = src[((size_t)(c * 128 + row) * 2 + b) * 16 + q];
    }
    __syncthreads();
    if (tid < KTAGS) {
        int tag = tid;
#pragma unroll 1
        for (int i = 127; i >= 0; --i) tag = bl[i][tag];
        cmap[(c * 2 + b) * 64 + tid] = (unsigned char)tag;
    }
}

__global__ void vit_boundary(const unsigned char* __restrict__ cmap,
                             const int* __restrict__ lastinfo,
                             int* __restrict__ xbound, int nch)
{
    int b = threadIdx.x;
    if (b < BATCH) {
        int tag = lastinfo[b];
        for (int c = nch - 1; c >= 0; --c) {
            xbound[c * 2 + b] = tag;             // tag at end of chunk c
            tag = cmap[(c * 2 + b) * 64 + tag];  // tag at end of chunk c-1
        }
    }
}

__global__ __launch_bounds__(64) void vit_emit(
    const unsigned char* __restrict__ bp, const int* __restrict__ xbound,
    float* __restrict__ out)
{
    int c = blockIdx.x, b = blockIdx.y;
    __shared__ unsigned char bl[128][64];
    int tid = threadIdx.x;
    const unsigned int* src = (const unsigned int*)bp;
    for (int i = tid; i < 128 * 16; i += 64) {
        int row = i >> 4, q = i & 15;
        ((unsigned int*)&bl[row][0])[q] = src[((size_t)(c * 128 + row) * 2 + b) * 16 + q];
    }
    __syncthreads();
    if (tid == 0) {
        int tag = xbound[c * 2 + b];
        for (int i = 127; i >= 0; --i) {
            out[2 + (size_t)(c * 128 + i) * 2 + b] = (float)tag;
            tag = bl[i][tag];
        }
    }
}

extern "C" void kernel_launch(void* const* d_in, const int* in_sizes, int n_in,
                              void* d_out, int out_size, void* d_ws, size_t ws_size,
                              hipStream_t stream) {
    const float* sent = (const float*)d_in[0];
    const float* w1 = (const float*)d_in[1];  const float* b1 = (const float*)d_in[2];
    const float* w2 = (const float*)d_in[3];  const float* b2 = (const float*)d_in[4];
    const float* w3 = (const float*)d_in[5];  const float* b3 = (const float*)d_in[6];
    const float* w4 = (const float*)d_in[7];  const float* b4 = (const float*)d_in[8];
    const float* w5 = (const float*)d_in[9];  const float* b5 = (const float*)d_in[10];
    const float* fw = (const float*)d_in[11]; const float* fb = (const float*)d_in[12];
    const float* trans = (const float*)d_in[13];

    const int B = BATCH;
    const int T = in_sizes[0] / (B * 3);     // 8192

    // workspace layout (fp32 activations, rolling 3 buffers)
    char* ws = (char*)d_ws;
    const size_t MB = 1024 * 1024;
    float* bufA = (float*)(ws);                       // 32 MiB each
    float* bufB = (float*)(ws + 32 * MB);
    float* bufC = (float*)(ws + 64 * MB);
    float* feats = (float*)(ws + 96 * MB);            // (T,2,64) padded, 4 MiB
    unsigned char* bp = (unsigned char*)(ws + 100 * MB);  // (T,2,64) bytes, 1 MiB
    unsigned char* cmap = (unsigned char*)(ws + 101 * MB);
    int* xbound = (int*)(ws + 101 * MB + 8192);
    int* lastinfo = xbound + 2 * (T / 128);
    float* outp = (float*)d_out;

    // CNN chain: A=in2, B=in3, C=in4, then in5->A, c5->B
    conv1_kernel<<<dim3(T / 256, HID, B), 256, 0, stream>>>(sent, w1, b1, bufA, T, B);
    conv_kernel<3, false><<<dim3(T / 64, HID / 64, B), 256, 0, stream>>>(bufA, nullptr, w2, b2, bufB, T);
    conv_kernel<3, true ><<<dim3(T / 64, HID / 64, B), 256, 0, stream>>>(bufB, bufA, w3, b3, bufC, T);
    conv_kernel<3, true ><<<dim3(T / 64, HID / 64, B), 256, 0, stream>>>(bufC, bufB, w4, b4, bufA, T);
    conv_kernel<5, true ><<<dim3(T / 64, HID / 64, B), 256, 0, stream>>>(bufA, bufC, w5, b5, bufB, T);
    fc_kernel<<<dim3(T / 64, B), 256, 0, stream>>>(bufB, fw, fb, feats, T);

    // Viterbi
    viterbi_fwd<<<dim3(B), 256, 0, stream>>>(feats, trans, outp, bp, lastinfo, T);
    vit_chunkmap<<<dim3(T / 128, B), 64, 0, stream>>>(bp, cmap);
    vit_boundary<<<dim3(1), 64, 0, stream>>>(cmap, lastinfo, xbound, T / 128);
    vit_emit<<<dim3(T / 128, B), 64, 0, stream>>>(bp, xbound, outp);
}

// Round 2
// 5491.981 us; speedup vs baseline: 1.5228x; 1.5228x over previous
//
#include <hip/hip_runtime.h>

#define BATCH 2
#define HID 512
#define KTAGS 60
#define NEGV -10000.0f
#define NINF -3.0e38f

// ---------------- conv1: sentence (T,B,3) -> y (B,512,T), relu ----------------
__global__ __launch_bounds__(256) void conv1_kernel(
    const float* __restrict__ sent, const float* __restrict__ w1,
    const float* __restrict__ b1, float* __restrict__ y, int T, int B)
{
    int t = blockIdx.x * 256 + threadIdx.x;
    int c = blockIdx.y;
    int b = blockIdx.z;
    if (t >= T) return;
    float acc = b1[c];
#pragma unroll
    for (int dk = 0; dk < 3; ++dk) {
        int tt = t + dk - 1;
        if (tt >= 0 && tt < T) {
#pragma unroll
            for (int ci = 0; ci < 3; ++ci)
                acc += sent[(size_t)tt * (B * 3) + b * 3 + ci] * w1[c * 9 + ci * 3 + dk];
        }
    }
    y[((size_t)b * HID + c) * T + t] = fmaxf(acc, 0.f);
}

// ---------------- weight transpose: w[co][ci][dk] -> wt[ci][dk][co] (exact permutation) ----------------
__global__ __launch_bounds__(256) void wtrans_kernel(
    const float* __restrict__ w, float* __restrict__ wt, int K)
{
    int idx = blockIdx.x * 256 + threadIdx.x;
    int total = HID * HID * K;
    if (idx >= total) return;
    int co = idx / (HID * K);
    int rem = idx % (HID * K);
    int ci = rem / K, dk = rem % K;
    wt[((size_t)ci * K + dk) * HID + co] = w[idx];
}

// ---------------- generic conv: y = relu(conv(x1 (+x2), wt) + bias) ----------------
// 64t x 128co tile, 256 threads, 4t x 8co per thread. wt layout [ci][dk][co].
template<int KTAP, bool RES>
__global__ __launch_bounds__(256) void conv_kernel(
    const float* __restrict__ x1, const float* __restrict__ x2,
    const float* __restrict__ wt, const float* __restrict__ bias,
    float* __restrict__ y, int T)
{
    const int PAD = KTAP / 2;
    const int t0 = blockIdx.x * 64;
    const int co0 = blockIdx.y * 128;
    const int b = blockIdx.z;
    __shared__ float Xs[16][72];            // window [t0-2, t0+66)
    __shared__ float Ws[16][KTAP][128];
    const int tid = threadIdx.x;
    const int tx = tid & 15;                // t quad (4 t each)
    const int ty = tid >> 4;                // co group (8 co each)
    float acc[8][4] = {};
    const size_t plane = (size_t)HID * T;
    const float* xa = x1 + (size_t)b * plane;
    const float* xb = RES ? (x2 + (size_t)b * plane) : nullptr;

    for (int c0 = 0; c0 < HID; c0 += 16) {
        for (int i = tid; i < 16 * 68; i += 256) {
            int ci = i / 68, tt = i % 68;
            int t = t0 + tt - 2;
            float v = 0.f;
            if (t >= 0 && t < T) {
                size_t off = (size_t)(c0 + ci) * T + t;
                v = xa[off];
                if (RES) v += xb[off];
            }
            Xs[ci][tt] = v;
        }
        for (int i = tid; i < 16 * KTAP * 32; i += 256) {
            int c4 = i & 31;
            int r = i >> 5;
            int dk = r % KTAP, ci = r / KTAP;
            *(float4*)&Ws[ci][dk][c4 * 4] =
                *(const float4*)&wt[(((size_t)(c0 + ci) * KTAP + dk) * HID) + co0 + c4 * 4];
        }
        __syncthreads();
#pragma unroll 4
        for (int ci = 0; ci < 16; ++ci) {
            float f8[8];
            *(float4*)&f8[0] = *(const float4*)&Xs[ci][tx * 4];
            *(float4*)&f8[4] = *(const float4*)&Xs[ci][tx * 4 + 4];
#pragma unroll
            for (int dk = 0; dk < KTAP; ++dk) {
                float wv[8];
                *(float4*)&wv[0] = *(const float4*)&Ws[ci][dk][ty * 8];
                *(float4*)&wv[4] = *(const float4*)&Ws[ci][dk][ty * 8 + 4];
#pragma unroll
                for (int r = 0; r < 8; ++r)
#pragma unroll
                    for (int c = 0; c < 4; ++c)
                        acc[r][c] = fmaf(wv[r], f8[c + dk + (2 - PAD)], acc[r][c]);
            }
        }
        __syncthreads();
    }
#pragma unroll
    for (int r = 0; r < 8; ++r) {
        int co = co0 + ty * 8 + r;
        float bv = bias[co];
#pragma unroll
        for (int c = 0; c < 4; ++c) {
            int t = t0 + tx * 4 + c;
            float v = acc[r][c] + bv;
            y[(size_t)b * plane + (size_t)co * T + t] = fmaxf(v, 0.f);
        }
    }
}

// ---------------- FC: feats[(t*2+b)*64+k] = dot(c5[b,:,t], fc_w[k,:]) + fc_b[k] ----------------
__global__ __launch_bounds__(256) void fc_kernel(
    const float* __restrict__ x, const float* __restrict__ fw,
    const float* __restrict__ fb, float* __restrict__ feats, int T)
{
    int t0 = blockIdx.x * 64, b = blockIdx.y;
    __shared__ float Xs[64][65];
    __shared__ float Ws[64][60];
    int tid = threadIdx.x;
    int k = tid & 63, tq = tid >> 6;
    float acc[16] = {};
    const float* xb = x + (size_t)b * HID * T;
    for (int c0 = 0; c0 < HID; c0 += 64) {
        for (int i = tid; i < 64 * 64; i += 256) {
            int ci = i >> 6, tt = i & 63;
            Xs[ci][tt] = xb[(size_t)(c0 + ci) * T + t0 + tt];
        }
        for (int i = tid; i < 64 * 60; i += 256) {
            int kk = i % 60, ci = i / 60;
            Ws[ci][kk] = fw[(size_t)kk * HID + c0 + ci];
        }
        __syncthreads();
        if (k < KTAGS) {
#pragma unroll 8
            for (int ci = 0; ci < 64; ++ci) {
                float wv = Ws[ci][k];
#pragma unroll
                for (int i = 0; i < 16; ++i)
                    acc[i] = fmaf(wv, Xs[ci][tq * 16 + i], acc[i]);
            }
        }
        __syncthreads();
    }
    if (k < KTAGS) {
        float bv = fb[k];
#pragma unroll
        for (int i = 0; i < 16; ++i) {
            int t = t0 + tq * 16 + i;
            feats[((size_t)t * 2 + b) * 64 + k] = acc[i] + bv;
        }
    }
}

// ---------------- Viterbi forward: max-only, single wave per batch, no barriers ----------------
// Exactness: max over the identical set of fl(fv[p]+trans[n][p]) values; masked bulk
// (-10000 exactly) folded via monotone rounding: max_p fl(fv[p]-1e4) = fl(max_p fv[p] - 1e4).
// Sparsity: row n>=2 unmasked prevs = {0, 1, n-1}; rows 0,1 dense; bulk = maxExcl(n-1)-1e4.
__global__ __launch_bounds__(64) void viterbi_fwd(
    const float* __restrict__ feats, const float* __restrict__ trans,
    float* __restrict__ fvbuf, int T)
{
    int b = blockIdx.x;
    int l = threadIdx.x;
    bool act = l < KTAGS;
    float tr0 = act ? trans[0 * KTAGS + l] : NINF;      // trans[0][prev=l]
    float tr1 = act ? trans[1 * KTAGS + l] : NINF;      // trans[1][prev=l]
    float tc0 = act ? trans[l * KTAGS + 0] : NINF;      // trans[next=l][0]
    float tc1 = act ? trans[l * KTAGS + 1] : NINF;      // trans[next=l][1]
    float trc = (l >= 2 && act) ? trans[l * KTAGS + (l - 1)] : NINF;  // chain (actual value, may be -1e4)
    float fv = act ? ((l == 58) ? 0.f : NEGV) : NINF;   // START_TAG = 58
    fvbuf[(size_t)(0 * 2 + b) * 64 + l] = fv;
    float feat = feats[(size_t)(0 * 2 + b) * 64 + l];
    for (int t = 0; t < T; ++t) {
        float featn = 0.f;
        if (t + 1 < T) featn = feats[((size_t)(t + 1) * 2 + b) * 64 + l];  // prefetch
        // dense rows 0 and 1: butterfly max over all prevs (includes masked -1e4 entries exactly)
        float a0 = fv + tr0;
        float a1 = fv + tr1;
#pragma unroll
        for (int d = 1; d < 64; d <<= 1) {
            a0 = fmaxf(a0, __shfl_xor(a0, d, 64));
            a1 = fmaxf(a1, __shfl_xor(a1, d, 64));
        }
        // prefix/suffix max of fv over prevs [2,63] for the masked bulk
        float fvm = (l < 2) ? NINF : fv;
        float pre = fvm, suf = fvm;
#pragma unroll
        for (int d = 1; d < 64; d <<= 1) {
            pre = fmaxf(pre, __shfl_up(pre, d, 64));     // lanes < d keep own (identity)
            suf = fmaxf(suf, __shfl_down(suf, d, 64));
        }
        float pre2 = __shfl_up(pre, 2, 64);              // pre[l-2]
        float mex = fmaxf(pre2, suf);                    // max over p in [2,63]\{l-1}
        float bulk = mex + NEGV;
        float cfv = __shfl_up(fv, 1, 64);                // fv[l-1]
        float cc = cfv + trc;                            // chain candidate
        float fv0b = __shfl(fv, 0, 64);
        float fv1b = __shfl(fv, 1, 64);
        float e0 = fv0b + tc0;
        float e1 = fv1b + tc1;
        float gen = fmaxf(fmaxf(fmaxf(e0, e1), cc), bulk);
        float m = (l == 0) ? a0 : ((l == 1) ? a1 : gen);
        fv = m + feat;
        if (l >= KTAGS) fv = NINF;
        fvbuf[((size_t)(t + 1) * 2 + b) * 64 + l] = fv;
        feat = featn;
    }
}

// ---------------- backpointers, fully parallel post-pass (exact first-index argmax) ----------------
__global__ __launch_bounds__(256) void bptr_kernel(
    const float* __restrict__ fvbuf, const float* __restrict__ trans,
    unsigned char* __restrict__ bp, int T)
{
    int b = blockIdx.y;
    int t0 = blockIdx.x * 4;
    __shared__ float trT[KTAGS][64];   // trT[p][next]
    __shared__ float fvs[4][64];
    int tid = threadIdx.x;
    for (int i = tid; i < KTAGS * KTAGS; i += 256) {
        int nx = i % KTAGS, p = i / KTAGS;   // conflict-free LDS writes
        trT[p][nx] = trans[(size_t)nx * KTAGS + p];
    }
    {
        int w = tid >> 6, l = tid & 63;
        fvs[w][l] = fvbuf[((size_t)(t0 + w) * 2 + b) * 64 + l];
    }
    __syncthreads();
    int w = tid >> 6, nx = tid & 63;
    if (nx < KTAGS) {
        float m = NINF; int am = 0;
        for (int p = 0; p < KTAGS; ++p) {
            float s = fvs[w][p] + trT[p][nx];
            if (s > m) { m = s; am = p; }    // strict > keeps FIRST max index
        }
        bp[((size_t)(t0 + w) * 2 + b) * 64 + nx] = (unsigned char)am;
    }
}

// ---------------- backtrace (chunked, exact) ----------------
__global__ __launch_bounds__(64) void vit_chunkmap(
    const unsigned char* __restrict__ bp, unsigned char* __restrict__ cmap)
{
    int c = blockIdx.x, b = blockIdx.y;
    __shared__ unsigned char bl[128][64];
    int tid = threadIdx.x;
    const unsigned int* src = (const unsigned int*)bp;
    for (int i = tid; i < 128 * 16; i += 64) {
        int row = i >> 4, q = i & 15;
        ((unsigned int*)&bl[row][0])[q] = src[((size_t)(c * 128 + row) * 2 + b) * 16 + q];
    }
    __syncthreads();
    if (tid < KTAGS) {
        int tag = tid;
#pragma unroll 1
        for (int i = 127; i >= 0; --i) tag = bl[i][tag];
        cmap[(c * 2 + b) * 64 + tid] = (unsigned char)tag;
    }
}

__global__ void vit_boundary(const unsigned char* __restrict__ cmap,
                             const float* __restrict__ fvbuf,
                             const float* __restrict__ trans,
                             int* __restrict__ xbound, float* __restrict__ out,
                             int nch, int T)
{
    int b = threadIdx.x;
    if (b < BATCH) {
        const float* fvT = fvbuf + ((size_t)T * 2 + b) * 64;
        float m = NINF; int am = 0;
        for (int p = 0; p < KTAGS; ++p) {
            float s = fvT[p] + trans[59 * KTAGS + p];   // STOP_TAG row
            if (s > m) { m = s; am = p; }
        }
        out[b] = m;
        int tag = am;
        for (int c = nch - 1; c >= 0; --c) {
            xbound[c * 2 + b] = tag;
            tag = cmap[(c * 2 + b) * 64 + tag];
        }
    }
}

__global__ __launch_bounds__(64) void vit_emit(
    const unsigned char* __restrict__ bp, const int* __restrict__ xbound,
    float* __restrict__ out)
{
    int c = blockIdx.x, b = blockIdx.y;
    __shared__ unsigned char bl[128][64];
    int tid = threadIdx.x;
    const unsigned int* src = (const unsigned int*)bp;
    for (int i = tid; i < 128 * 16; i += 64) {
        int row = i >> 4, q = i & 15;
        ((unsigned int*)&bl[row][0])[q] = src[((size_t)(c * 128 + row) * 2 + b) * 16 + q];
    }
    __syncthreads();
    if (tid == 0) {
        int tag = xbound[c * 2 + b];
        for (int i = 127; i >= 0; --i) {
            out[2 + (size_t)(c * 128 + i) * 2 + b] = (float)tag;
            tag = bl[i][tag];
        }
    }
}

extern "C" void kernel_launch(void* const* d_in, const int* in_sizes, int n_in,
                              void* d_out, int out_size, void* d_ws, size_t ws_size,
                              hipStream_t stream) {
    const float* sent = (const float*)d_in[0];
    const float* w1 = (const float*)d_in[1];  const float* b1 = (const float*)d_in[2];
    const float* w2 = (const float*)d_in[3];  const float* b2 = (const float*)d_in[4];
    const float* w3 = (const float*)d_in[5];  const float* b3 = (const float*)d_in[6];
    const float* w4 = (const float*)d_in[7];  const float* b4 = (const float*)d_in[8];
    const float* w5 = (const float*)d_in[9];  const float* b5 = (const float*)d_in[10];
    const float* fw = (const float*)d_in[11]; const float* fb = (const float*)d_in[12];
    const float* trans = (const float*)d_in[13];

    const int B = BATCH;
    const int T = in_sizes[0] / (B * 3);     // 8192

    // ws layout (lifetime-overlaid):
    //   A @ 0, Bb @ 32M, C @ 64M (each 33.56MB activation)
    //   SLOT @ ~100.7M: per-layer transposed weights (<=5.25MB); feats reuses SLOT after conv5
    //   fvbuf overlays C (dead after conv5); bp/cmap/xbound overlay A (dead after conv5)
    char* ws = (char*)d_ws;
    const size_t SZBUF = (size_t)2 * HID * 8192 * 4;       // 33,554,432
    float* bufA = (float*)(ws);
    float* bufB = (float*)(ws + SZBUF);
    float* bufC = (float*)(ws + 2 * SZBUF);
    float* wslot = (float*)(ws + 3 * SZBUF);               // 5.25MB max
    float* feats = wslot;                                  // after conv5
    float* fvbuf = bufC;                                   // after conv5, (T+1)*2*64*4 = 4.19MB
    unsigned char* bp = (unsigned char*)ws;                // after viterbi_fwd, 1.05MB
    unsigned char* cmap = (unsigned char*)(ws + 2 * 1024 * 1024);
    int* xbound = (int*)(ws + 3 * 1024 * 1024);
    float* outp = (float*)d_out;

    conv1_kernel<<<dim3(T / 256, HID, B), 256, 0, stream>>>(sent, w1, b1, bufA, T, B);

    wtrans_kernel<<<(HID * HID * 3 + 255) / 256, 256, 0, stream>>>(w2, wslot, 3);
    conv_kernel<3, false><<<dim3(T / 64, HID / 128, B), 256, 0, stream>>>(bufA, nullptr, wslot, b2, bufB, T);
    wtrans_kernel<<<(HID * HID * 3 + 255) / 256, 256, 0, stream>>>(w3, wslot, 3);
    conv_kernel<3, true ><<<dim3(T / 64, HID / 128, B), 256, 0, stream>>>(bufB, bufA, wslot, b3, bufC, T);
    wtrans_kernel<<<(HID * HID * 3 + 255) / 256, 256, 0, stream>>>(w4, wslot, 3);
    conv_kernel<3, true ><<<dim3(T / 64, HID / 128, B), 256, 0, stream>>>(bufC, bufB, wslot, b4, bufA, T);
    wtrans_kernel<<<(HID * HID * 5 + 255) / 256, 256, 0, stream>>>(w5, wslot, 5);
    conv_kernel<5, true ><<<dim3(T / 64, HID / 128, B), 256, 0, stream>>>(bufA, bufC, wslot, b5, bufB, T);

    fc_kernel<<<dim3(T / 64, B), 256, 0, stream>>>(bufB, fw, fb, feats, T);

    viterbi_fwd<<<dim3(B), 64, 0, stream>>>(feats, trans, fvbuf, T);
    bptr_kernel<<<dim3(T / 4, B), 256, 0, stream>>>(fvbuf, trans, bp, T);
    vit_chunkmap<<<dim3(T / 128, B), 64, 0, stream>>>(bp, cmap);
    vit_boundary<<<dim3(1), 64, 0, stream>>>(cmap, fvbuf, trans, xbound, outp, T / 128, T);
    vit_emit<<<dim3(T / 128, B), 64, 0, stream>>>(bp, xbound, outp);
}

// Round 3
// 4607.135 us; speedup vs baseline: 1.8152x; 1.1921x over previous
//
#include <hip/hip_runtime.h>

#define BATCH 2
#define HID 512
#define KTAGS 60
#define NEGV -10000.0f
#define NINF -3.0e38f

// ---------------- DPP helpers ----------------
template<int CTRL>
__device__ __forceinline__ float dmax(float x) {
    int r = __builtin_amdgcn_update_dpp(__float_as_int(x), __float_as_int(x),
                                        CTRL, 0xf, 0xf, false);
    return fmaxf(x, __int_as_float(r));
}
template<int CTRL>
__device__ __forceinline__ float dmov(float x, float old) {
    int r = __builtin_amdgcn_update_dpp(__float_as_int(old), __float_as_int(x),
                                        CTRL, 0xf, 0xf, false);
    return __int_as_float(r);
}
template<int L>
__device__ __forceinline__ float rdl(float x) {
    return __int_as_float(__builtin_amdgcn_readlane(__float_as_int(x), L));
}
// full-64 max -> result valid in lane 63 (rocPRIM sequence)
__device__ __forceinline__ float red64(float x) {
    x = dmax<0x111>(x);  // row_shr:1
    x = dmax<0x112>(x);  // row_shr:2
    x = dmax<0x114>(x);  // row_shr:4
    x = dmax<0x118>(x);  // row_shr:8
    x = dmax<0x142>(x);  // row_bcast15
    x = dmax<0x143>(x);  // row_bcast31
    return x;
}

// ---------------- conv1: sentence (T,B,3) -> y (B,512,T), relu ----------------
__global__ __launch_bounds__(256) void conv1_kernel(
    const float* __restrict__ sent, const float* __restrict__ w1,
    const float* __restrict__ b1, float* __restrict__ y, int T, int B)
{
    int t = blockIdx.x * 256 + threadIdx.x;
    int c = blockIdx.y;
    int b = blockIdx.z;
    if (t >= T) return;
    float acc = b1[c];
#pragma unroll
    for (int dk = 0; dk < 3; ++dk) {
        int tt = t + dk - 1;
        if (tt >= 0 && tt < T) {
#pragma unroll
            for (int ci = 0; ci < 3; ++ci)
                acc += sent[(size_t)tt * (B * 3) + b * 3 + ci] * w1[c * 9 + ci * 3 + dk];
        }
    }
    y[((size_t)b * HID + c) * T + t] = fmaxf(acc, 0.f);
}

// ---------------- weight transpose: w[co][ci][dk] -> wt[ci][dk][co] ----------------
__global__ __launch_bounds__(256) void wtrans_kernel(
    const float* __restrict__ w, float* __restrict__ wt, int K)
{
    int idx = blockIdx.x * 256 + threadIdx.x;
    int total = HID * HID * K;
    if (idx >= total) return;
    int co = idx / (HID * K);
    int rem = idx % (HID * K);
    int ci = rem / K, dk = rem % K;
    wt[((size_t)ci * K + dk) * HID + co] = w[idx];
}

// ---------------- generic conv: y = relu(conv(x1 (+x2), wt) + bias) ----------------
// 128t x 128co tile, 256 threads; per thread 2x2 quadrants of 4co x 4t (split 64 apart
// so all LDS reads have stride-4-float lane addressing = conflict-free).
template<int KTAP, bool RES>
__global__ __launch_bounds__(256) void conv_kernel(
    const float* __restrict__ x1, const float* __restrict__ x2,
    const float* __restrict__ wt, const float* __restrict__ bias,
    float* __restrict__ y, int T)
{
    const int PAD = KTAP / 2;
    const int t0 = blockIdx.x * 128;
    const int co0 = blockIdx.y * 128;
    const int b = blockIdx.z;
    __shared__ float Xs[16][136];            // Xs[ci][tt] = x[t0+tt-2], tt in [0,132)
    __shared__ float Ws[16][KTAP][128];
    const int tid = threadIdx.x;
    const int tx = tid & 15;
    const int ty = tid >> 4;
    float acc[2][2][4][4] = {};              // [tBlk][coBlk][r=co][c=t]
    const size_t plane = (size_t)HID * T;
    const float* xa = x1 + (size_t)b * plane;
    const float* xb = RES ? (x2 + (size_t)b * plane) : nullptr;

    for (int c0 = 0; c0 < HID; c0 += 16) {
        // X stage: 16 rows x 66 float2 (8B aligned both sides)
        for (int i = tid; i < 16 * 66; i += 256) {
            int ci = i / 66, q = i % 66;
            int t = t0 + q * 2 - 2;
            float2 v = {0.f, 0.f};
            size_t off = (size_t)(c0 + ci) * T;
            if (t >= 0 && t + 1 < T) {
                v = *(const float2*)(xa + off + t);
                if (RES) { float2 u = *(const float2*)(xb + off + t); v.x += u.x; v.y += u.y; }
            } else {
                if (t >= 0 && t < T)         { v.x = xa[off + t];     if (RES) v.x += xb[off + t]; }
                if (t + 1 >= 0 && t + 1 < T) { v.y = xa[off + t + 1]; if (RES) v.y += xb[off + t + 1]; }
            }
            *(float2*)&Xs[ci][q * 2] = v;
        }
        // W stage: float4, contiguous
        for (int i = tid; i < 16 * KTAP * 32; i += 256) {
            int c4 = i & 31, r = i >> 5;
            int dk = r % KTAP, ci = r / KTAP;
            *(float4*)&Ws[ci][dk][c4 * 4] =
                *(const float4*)&wt[(((size_t)(c0 + ci) * KTAP + dk) * HID) + co0 + c4 * 4];
        }
        __syncthreads();
#pragma unroll
        for (int ci = 0; ci < 16; ++ci) {
            float fA[8], fB[8];
            *(float4*)&fA[0] = *(const float4*)&Xs[ci][tx * 4];
            *(float4*)&fA[4] = *(const float4*)&Xs[ci][tx * 4 + 4];
            *(float4*)&fB[0] = *(const float4*)&Xs[ci][64 + tx * 4];
            *(float4*)&fB[4] = *(const float4*)&Xs[ci][64 + tx * 4 + 4];
#pragma unroll
            for (int dk = 0; dk < KTAP; ++dk) {
                float wA[4], wB[4];
                *(float4*)&wA[0] = *(const float4*)&Ws[ci][dk][ty * 4];
                *(float4*)&wB[0] = *(const float4*)&Ws[ci][dk][64 + ty * 4];
#pragma unroll
                for (int r = 0; r < 4; ++r)
#pragma unroll
                    for (int c = 0; c < 4; ++c) {
                        const int xi = c + dk + (2 - PAD);
                        acc[0][0][r][c] = fmaf(wA[r], fA[xi], acc[0][0][r][c]);
                        acc[0][1][r][c] = fmaf(wB[r], fA[xi], acc[0][1][r][c]);
                        acc[1][0][r][c] = fmaf(wA[r], fB[xi], acc[1][0][r][c]);
                        acc[1][1][r][c] = fmaf(wB[r], fB[xi], acc[1][1][r][c]);
                    }
            }
        }
        __syncthreads();
    }
#pragma unroll
    for (int tb = 0; tb < 2; ++tb)
#pragma unroll
        for (int cb = 0; cb < 2; ++cb)
#pragma unroll
            for (int r = 0; r < 4; ++r) {
                int co = co0 + cb * 64 + ty * 4 + r;
                float bv = bias[co];
                float4 o;
                o.x = fmaxf(acc[tb][cb][r][0] + bv, 0.f);
                o.y = fmaxf(acc[tb][cb][r][1] + bv, 0.f);
                o.z = fmaxf(acc[tb][cb][r][2] + bv, 0.f);
                o.w = fmaxf(acc[tb][cb][r][3] + bv, 0.f);
                *(float4*)&y[(size_t)b * plane + (size_t)co * T + t0 + tb * 64 + tx * 4] = o;
            }
}

// ---------------- FC -> featsT[b][k][T] (transposed for viterbi streaming) ----------------
__global__ __launch_bounds__(256) void fc_kernel(
    const float* __restrict__ x, const float* __restrict__ fw,
    const float* __restrict__ fb, float* __restrict__ featsT, int T)
{
    int t0 = blockIdx.x * 64, b = blockIdx.y;
    __shared__ float Xs[64][65];
    __shared__ float Ws[64][60];
    int tid = threadIdx.x;
    int k = tid & 63, tq = tid >> 6;
    float acc[16] = {};
    const float* xb = x + (size_t)b * HID * T;
    for (int c0 = 0; c0 < HID; c0 += 64) {
        for (int i = tid; i < 64 * 64; i += 256) {
            int ci = i >> 6, tt = i & 63;
            Xs[ci][tt] = xb[(size_t)(c0 + ci) * T + t0 + tt];
        }
        for (int i = tid; i < 64 * 60; i += 256) {
            int kk = i % 60, ci = i / 60;
            Ws[ci][kk] = fw[(size_t)kk * HID + c0 + ci];
        }
        __syncthreads();
        if (k < KTAGS) {
#pragma unroll 8
            for (int ci = 0; ci < 64; ++ci) {
                float wv = Ws[ci][k];
#pragma unroll
                for (int i = 0; i < 16; ++i)
                    acc[i] = fmaf(wv, Xs[ci][tq * 16 + i], acc[i]);
            }
        }
        __syncthreads();
    }
    float bv = (k < KTAGS) ? fb[k] : 0.f;
    float* dst = featsT + ((size_t)b * 64 + k) * T + t0 + tq * 16;
#pragma unroll
    for (int i = 0; i < 16; i += 4) {
        float4 o;
        o.x = (k < KTAGS) ? acc[i + 0] + bv : 0.f;
        o.y = (k < KTAGS) ? acc[i + 1] + bv : 0.f;
        o.z = (k < KTAGS) ? acc[i + 2] + bv : 0.f;
        o.w = (k < KTAGS) ? acc[i + 3] + bv : 0.f;
        *(float4*)&dst[i] = o;
    }
}

// ---------------- Viterbi forward: DPP reductions, 1 wave per batch ----------------
// Exact: rows 0,1 dense weighted max; rows>=2: max(e0,e1,chain,bulk) where
// bulk = max(fv[2:]) - 1e4 (inclusive of p=n-1 is exact since chain >= that candidate
// by monotone rounding, trans[n][n-1] > -1e4 always).
__global__ __launch_bounds__(64) void viterbi_fwd(
    const float* __restrict__ featsT, const float* __restrict__ trans,
    float* __restrict__ fvbuf, int T)
{
    const int b = blockIdx.x;
    const int l = threadIdx.x;
    const bool act = l < KTAGS;
    const float tr0 = act ? trans[0 * KTAGS + l] : NINF;
    const float tr1 = act ? trans[1 * KTAGS + l] : NINF;
    const float tc0 = act ? trans[l * KTAGS + 0] : NINF;
    const float tc1 = act ? trans[l * KTAGS + 1] : NINF;
    const float trc = (l >= 2 && act) ? trans[l * KTAGS + (l - 1)] : NINF;
    float fv = act ? ((l == 58) ? 0.f : NEGV) : NINF;   // START_TAG = 58
    fvbuf[(size_t)b * 64 + l] = fv;
    const float* fT = featsT + ((size_t)b * 64 + l) * T;
    float* fvb = fvbuf + (size_t)b * 64 + l;

    float4 cur = *(const float4*)&fT[0];

    auto step = [&](float feat, int tout) {
        float s0 = fv + tr0;
        float s1 = fv + tr1;
        float g = (l >= 2) ? fv : NINF;
        s0 = red64(s0); s1 = red64(s1); g = red64(g);
        float m0 = rdl<63>(s0), m1 = rdl<63>(s1), M = rdl<63>(g);
        float c = dmov<0x111>(fv, fv);       // row_shr:1 (row starts keep own)
        float f15 = rdl<15>(fv), f31 = rdl<31>(fv), f47 = rdl<47>(fv);
        c = (l == 16) ? f15 : (l == 32) ? f31 : (l == 48) ? f47 : c;
        float cc = c + trc;
        float e0 = rdl<0>(fv) + tc0;
        float e1 = rdl<1>(fv) + tc1;
        float gen = fmaxf(fmaxf(e0, e1), fmaxf(cc, M + NEGV));
        float m = (l == 0) ? m0 : (l == 1) ? m1 : gen;
        float nf = m + feat;
        fv = (l < KTAGS) ? nf : NINF;
        fvb[(size_t)tout * 128] = fv;
    };

    for (int tb = 0; tb < T; tb += 4) {
        float4 nxt;
        if (tb + 4 < T) nxt = *(const float4*)&fT[tb + 4];
        else            nxt = float4{0.f, 0.f, 0.f, 0.f};
        step(cur.x, tb + 1);
        step(cur.y, tb + 2);
        step(cur.z, tb + 3);
        step(cur.w, tb + 4);
        cur = nxt;
    }
}

// ---------------- backpointers (exact first-index argmax), 16 t per block ----------------
__global__ __launch_bounds__(256) void bptr_kernel(
    const float* __restrict__ fvbuf, const float* __restrict__ trans,
    unsigned char* __restrict__ bp, int T)
{
    int b = blockIdx.y;
    int t0 = blockIdx.x * 16;
    __shared__ float trT[KTAGS][64];
    __shared__ float fvs[16][64];
    int tid = threadIdx.x;
    for (int i = tid; i < KTAGS * 64; i += 256) {
        int p = i >> 6, nx = i & 63;
        trT[p][nx] = (nx < KTAGS) ? trans[(size_t)nx * KTAGS + p] : NINF;
    }
    for (int i = tid; i < 16 * 64; i += 256) {
        int w = i >> 6, l = i & 63;
        fvs[w][l] = fvbuf[((size_t)(t0 + w) * 2 + b) * 64 + l];
    }
    __syncthreads();
    int nx = tid & 63, w0 = tid >> 6;
    if (nx < KTAGS) {
#pragma unroll
        for (int j = 0; j < 4; ++j) {
            int w = w0 * 4 + j;
            float m = NINF; int am = 0;
            for (int p = 0; p < KTAGS; ++p) {
                float s = fvs[w][p] + trT[p][nx];
                if (s > m) { m = s; am = p; }    // strict > keeps FIRST max index
            }
            bp[((size_t)(t0 + w) * 2 + b) * 64 + nx] = (unsigned char)am;
        }
    }
}

// ---------------- backtrace (chunked, exact) ----------------
__global__ __launch_bounds__(64) void vit_chunkmap(
    const unsigned char* __restrict__ bp, unsigned char* __restrict__ cmap)
{
    int c = blockIdx.x, b = blockIdx.y;
    __shared__ unsigned char bl[128][64];
    int tid = threadIdx.x;
    const unsigned int* src = (const unsigned int*)bp;
    for (int i = tid; i < 128 * 16; i += 64) {
        int row = i >> 4, q = i & 15;
        ((unsigned int*)&bl[row][0])[q] = src[((size_t)(c * 128 + row) * 2 + b) * 16 + q];
    }
    __syncthreads();
    if (tid < KTAGS) {
        int tag = tid;
#pragma unroll 1
        for (int i = 127; i >= 0; --i) tag = bl[i][tag];
        cmap[(c * 2 + b) * 64 + tid] = (unsigned char)tag;
    }
}

__global__ void vit_boundary(const unsigned char* __restrict__ cmap,
                             const float* __restrict__ fvbuf,
                             const float* __restrict__ trans,
                             int* __restrict__ xbound, float* __restrict__ out,
                             int nch, int T)
{
    int b = threadIdx.x;
    if (b < BATCH) {
        const float* fvT = fvbuf + ((size_t)T * 2 + b) * 64;
        float m = NINF; int am = 0;
        for (int p = 0; p < KTAGS; ++p) {
            float s = fvT[p] + trans[59 * KTAGS + p];   // STOP_TAG row
            if (s > m) { m = s; am = p; }
        }
        out[b] = m;
        int tag = am;
        for (int c = nch - 1; c >= 0; --c) {
            xbound[c * 2 + b] = tag;
            tag = cmap[(c * 2 + b) * 64 + tag];
        }
    }
}

__global__ __launch_bounds__(64) void vit_emit(
    const unsigned char* __restrict__ bp, const int* __restrict__ xbound,
    float* __restrict__ out)
{
    int c = blockIdx.x, b = blockIdx.y;
    __shared__ unsigned char bl[128][64];
    int tid = threadIdx.x;
    const unsigned int* src = (const unsigned int*)bp;
    for (int i = tid; i < 128 * 16; i += 64) {
        int row = i >> 4, q = i & 15;
        ((unsigned int*)&bl[row][0])[q] = src[((size_t)(c * 128 + row) * 2 + b) * 16 + q];
    }
    __syncthreads();
    if (tid == 0) {
        int tag = xbound[c * 2 + b];
        for (int i = 127; i >= 0; --i) {
            out[2 + (size_t)(c * 128 + i) * 2 + b] = (float)tag;
            tag = bl[i][tag];
        }
    }
}

extern "C" void kernel_launch(void* const* d_in, const int* in_sizes, int n_in,
                              void* d_out, int out_size, void* d_ws, size_t ws_size,
                              hipStream_t stream) {
    const float* sent = (const float*)d_in[0];
    const float* w1 = (const float*)d_in[1];  const float* b1 = (const float*)d_in[2];
    const float* w2 = (const float*)d_in[3];  const float* b2 = (const float*)d_in[4];
    const float* w3 = (const float*)d_in[5];  const float* b3 = (const float*)d_in[6];
    const float* w4 = (const float*)d_in[7];  const float* b4 = (const float*)d_in[8];
    const float* w5 = (const float*)d_in[9];  const float* b5 = (const float*)d_in[10];
    const float* fw = (const float*)d_in[11]; const float* fb = (const float*)d_in[12];
    const float* trans = (const float*)d_in[13];

    const int B = BATCH;
    const int T = in_sizes[0] / (B * 3);     // 8192

    char* ws = (char*)d_ws;
    const size_t SZBUF = (size_t)2 * HID * 8192 * 4;       // 32 MiB
    float* bufA = (float*)(ws);
    float* bufB = (float*)(ws + SZBUF);
    float* bufC = (float*)(ws + 2 * SZBUF);
    float* wslot = (float*)(ws + 3 * SZBUF);               // weights, then featsT (4MB)
    float* featsT = wslot;
    float* fvbuf = bufC;                                   // after conv5
    unsigned char* bp = (unsigned char*)ws;                // after viterbi_fwd
    unsigned char* cmap = (unsigned char*)(ws + 2 * 1024 * 1024);
    int* xbound = (int*)(ws + 3 * 1024 * 1024);
    float* outp = (float*)d_out;

    conv1_kernel<<<dim3(T / 256, HID, B), 256, 0, stream>>>(sent, w1, b1, bufA, T, B);

    wtrans_kernel<<<(HID * HID * 3 + 255) / 256, 256, 0, stream>>>(w2, wslot, 3);
    conv_kernel<3, false><<<dim3(T / 128, HID / 128, B), 256, 0, stream>>>(bufA, nullptr, wslot, b2, bufB, T);
    wtrans_kernel<<<(HID * HID * 3 + 255) / 256, 256, 0, stream>>>(w3, wslot, 3);
    conv_kernel<3, true ><<<dim3(T / 128, HID / 128, B), 256, 0, stream>>>(bufB, bufA, wslot, b3, bufC, T);
    wtrans_kernel<<<(HID * HID * 3 + 255) / 256, 256, 0, stream>>>(w4, wslot, 3);
    conv_kernel<3, true ><<<dim3(T / 128, HID / 128, B), 256, 0, stream>>>(bufC, bufB, wslot, b4, bufA, T);
    wtrans_kernel<<<(HID * HID * 5 + 255) / 256, 256, 0, stream>>>(w5, wslot, 5);
    conv_kernel<5, true ><<<dim3(T / 128, HID / 128, B), 256, 0, stream>>>(bufA, bufC, wslot, b5, bufB, T);

    fc_kernel<<<dim3(T / 64, B), 256, 0, stream>>>(bufB, fw, fb, featsT, T);

    viterbi_fwd<<<dim3(B), 64, 0, stream>>>(featsT, trans, fvbuf, T);
    bptr_kernel<<<dim3(T / 16, B), 256, 0, stream>>>(fvbuf, trans, bp, T);
    vit_chunkmap<<<dim3(T / 128, B), 64, 0, stream>>>(bp, cmap);
    vit_boundary<<<dim3(1), 64, 0, stream>>>(cmap, fvbuf, trans, xbound, outp, T / 128, T);
    vit_emit<<<dim3(T / 128, B), 64, 0, stream>>>(bp, xbound, outp);
}